// Round 1
// baseline (778.135 us; speedup 1.0000x reference)
//
#include <hip/hip_runtime.h>
#include <hip/hip_bf16.h>

// MQA layer: B=2, S=2048, HID=1024, H=16, D=64.
// d_out = out [2,2048,1024] fp32 (4,194,304 floats) then attn [2,16,2048,2048] fp32.
// ws usage: ~46 MB (see offsets in kernel_launch).

typedef __attribute__((ext_vector_type(4))) float f32x4;
typedef __attribute__((ext_vector_type(8))) __bf16 bf16x8;
typedef __attribute__((ext_vector_type(4))) __bf16 bf16x4;

__device__ __forceinline__ f32x4 mfma16(bf16x8 a, bf16x8 b, f32x4 c) {
    return __builtin_amdgcn_mfma_f32_16x16x32_bf16(a, b, c, 0, 0, 0);
}

__device__ __forceinline__ void gload_lds16(const void* g, void* l) {
    typedef __attribute__((address_space(1))) const void gv_t;
    typedef __attribute__((address_space(3))) void lv_t;
    __builtin_amdgcn_global_load_lds((gv_t*)g, (lv_t*)l, 16, 0, 0);
}

// ---------------- convert f32 -> bf16 (vectorized) ----------------
__global__ __launch_bounds__(256) void cvt_f32_bf16(const float* __restrict__ in,
                                                    __bf16* __restrict__ out) {
    const size_t i = ((size_t)blockIdx.x * 256 + threadIdx.x) * 4;
    f32x4 v = *(const f32x4*)(in + i);
    bf16x4 o;
    o[0] = (__bf16)v[0]; o[1] = (__bf16)v[1]; o[2] = (__bf16)v[2]; o[3] = (__bf16)v[3];
    *(bf16x4*)(out + i) = o;
}

// ---------------- transpose+convert: [K][N] f32 -> [N][K] bf16 ----------------
__global__ __launch_bounds__(256) void transpose_cvt(const float* __restrict__ in,
                                                     __bf16* __restrict__ out,
                                                     int K, int N) {
    __shared__ __bf16 tl[64][72];
    const int k0 = blockIdx.y * 64, n0 = blockIdx.x * 64;
    const int tid = threadIdx.x;
#pragma unroll
    for (int i = 0; i < 16; ++i) {
        int idx = tid + i * 256;
        int r = idx >> 6, c = idx & 63;
        tl[c][r] = (__bf16)in[(size_t)(k0 + r) * N + n0 + c];
    }
    __syncthreads();
#pragma unroll
    for (int i = 0; i < 16; ++i) {
        int idx = tid + i * 256;
        int nn = idx >> 6, kk = idx & 63;
        out[(size_t)(n0 + nn) * K + k0 + kk] = tl[nn][kk];
    }
}

// ---------------- GEMM: C[M=4096][N] = A[4096][1024] @ Bt[N][1024]^T + bias ----------------
// OMODE 0: q-proj  -> bf16 [4096][1024], scaled by 0.125 (folds 1/sqrt(D))
// OMODE 1: k-proj  -> bf16 [4096][64]
// OMODE 2: v-proj  -> bf16 Vt [2][64][2048] (transposed write)
// OMODE 3: dense   -> f32  [4096][1024] (d_out)
template <int BN, int OMODE>
__global__ __launch_bounds__(256) void gemm_kernel(const __bf16* __restrict__ A,
                                                   const __bf16* __restrict__ Bt,
                                                   const float* __restrict__ bias,
                                                   void* __restrict__ outp) {
    constexpr int FN = BN / 32;          // 16x16 col-frags per wave (wave tile 64 x BN/2)
    __shared__ char lds[128 * 128 + BN * 128];
    char* aLds = lds;
    char* bLds = lds + 128 * 128;
    const int tid = threadIdx.x;
    const int w = tid >> 6, l = tid & 63;
    const int lq = l & 15, lg = l >> 4;
    const int wr = w >> 1, wc = w & 1;
    const int m0 = blockIdx.y * 128, n0 = blockIdx.x * BN;

    f32x4 acc[4][FN];
#pragma unroll
    for (int mt = 0; mt < 4; ++mt)
#pragma unroll
        for (int nt = 0; nt < FN; ++nt) acc[mt][nt] = (f32x4){0.f, 0.f, 0.f, 0.f};

    for (int kk = 0; kk < 16; ++kk) {   // K=1024, BK=64
        __syncthreads();
        // stage A tile [128][64] bf16, linear LDS dest + inverse-swizzled source
        const char* aSrc = (const char*)A + (size_t)m0 * 2048 + kk * 128;
#pragma unroll
        for (int c = 0; c < 4; ++c) {
            int off = (w * 4 + c) * 1024 + l * 16;
            int r = off >> 7, cb = off & 127;
            gload_lds16(aSrc + (size_t)r * 2048 + (cb ^ ((r & 7) << 4)),
                        aLds + (w * 4 + c) * 1024);
        }
        const char* bSrc = (const char*)Bt + (size_t)n0 * 2048 + kk * 128;
#pragma unroll
        for (int c = 0; c < FN; ++c) {
            int off = (w * FN + c) * 1024 + l * 16;
            int r = off >> 7, cb = off & 127;
            gload_lds16(bSrc + (size_t)r * 2048 + (cb ^ ((r & 7) << 4)),
                        bLds + (w * FN + c) * 1024);
        }
        asm volatile("s_waitcnt vmcnt(0)" ::: "memory");
        __syncthreads();

#pragma unroll
        for (int s = 0; s < 2; ++s) {
            bf16x8 af[4], bfv[FN];
#pragma unroll
            for (int mt = 0; mt < 4; ++mt) {
                int row = wr * 64 + mt * 16 + lq;
                af[mt] = *(const bf16x8*)(aLds + row * 128 + ((s * 64 + lg * 16) ^ ((row & 7) << 4)));
            }
#pragma unroll
            for (int nt = 0; nt < FN; ++nt) {
                int row = wc * (BN / 2) + nt * 16 + lq;
                bfv[nt] = *(const bf16x8*)(bLds + row * 128 + ((s * 64 + lg * 16) ^ ((row & 7) << 4)));
            }
#pragma unroll
            for (int mt = 0; mt < 4; ++mt)
#pragma unroll
                for (int nt = 0; nt < FN; ++nt)
                    acc[mt][nt] = mfma16(af[mt], bfv[nt], acc[mt][nt]);
        }
    }

    // epilogue. D layout: col = lane&15, row = (lane>>4)*4 + reg (m89/m91 verified)
#pragma unroll
    for (int nt = 0; nt < FN; ++nt) {
        const int n = n0 + wc * (BN / 2) + nt * 16 + lq;
        const float bv = bias[n];
#pragma unroll
        for (int mt = 0; mt < 4; ++mt) {
            const int mBase = m0 + wr * 64 + mt * 16 + lg * 4;
            if constexpr (OMODE == 0) {
                __bf16* o = (__bf16*)outp;
#pragma unroll
                for (int r2 = 0; r2 < 4; ++r2)
                    o[(size_t)(mBase + r2) * 1024 + n] = (__bf16)((acc[mt][nt][r2] + bv) * 0.125f);
            } else if constexpr (OMODE == 1) {
                __bf16* o = (__bf16*)outp;
#pragma unroll
                for (int r2 = 0; r2 < 4; ++r2)
                    o[(size_t)(mBase + r2) * 64 + n] = (__bf16)(acc[mt][nt][r2] + bv);
            } else if constexpr (OMODE == 2) {
                bf16x4 o4;
#pragma unroll
                for (int r2 = 0; r2 < 4; ++r2) o4[r2] = (__bf16)(acc[mt][nt][r2] + bv);
                __bf16* o = (__bf16*)outp;  // Vt [b][64][2048]; 4 regs = 4 consecutive s
                *(bf16x4*)(o + ((size_t)((mBase >> 11) * 64 + n)) * 2048 + (mBase & 2047)) = o4;
            } else {
                float* o = (float*)outp;
#pragma unroll
                for (int r2 = 0; r2 < 4; ++r2)
                    o[(size_t)(mBase + r2) * 1024 + n] = acc[mt][nt][r2] + bv;
            }
        }
    }
}

// ---------------- fused attention ----------------
// grid (32 qblocks, 16 heads, 2 batch), 4 waves; wave owns 16 q rows.
// E_T[k][q] = mfma(A=K rows, B=Q rows) so lane owns q=lane&15 (col), k=(lane>>4)*4+reg.
__device__ __forceinline__ void compute_et(const char* kLds, bf16x8 qf0, bf16x8 qf1,
                                           int lq, int lg, f32x4* et) {
#pragma unroll
    for (int kt = 0; kt < 8; ++kt) {
        const int row = kt * 16 + lq;
        const int swz = (row & 7) << 4;
        bf16x8 a0 = *(const bf16x8*)(kLds + row * 128 + ((lg * 16) ^ swz));
        bf16x8 a1 = *(const bf16x8*)(kLds + row * 128 + ((64 + lg * 16) ^ swz));
        f32x4 acc = (f32x4){0.f, 0.f, 0.f, 0.f};
        acc = mfma16(a0, qf0, acc);
        acc = mfma16(a1, qf1, acc);
        et[kt] = acc;
    }
}

__global__ __launch_bounds__(256) void attn_fused(const __bf16* __restrict__ qp,
                                                  const __bf16* __restrict__ kp,
                                                  const __bf16* __restrict__ vt,
                                                  float* __restrict__ attn_out,
                                                  __bf16* __restrict__ ctx) {
    __shared__ char lds[48 * 1024];
    char* kLds = lds;                 // 16KB: 128 rows x 128B, XOR-swizzled
    char* vLds = lds + 16 * 1024;     // 16KB: 64 rows x 256B (Vt tile), XOR-swizzled
    const int tid = threadIdx.x;
    const int w = tid >> 6, l = tid & 63;
    const int lq = l & 15, lg = l >> 4;
    char* pLds = lds + 32 * 1024 + w * 4096;  // per-wave P [16 q][128 k] bf16

    const int qb = blockIdx.x, h = blockIdx.y, b = blockIdx.z;
    const int qr0 = qb * 64 + w * 16;

    // Q fragment (B-operand): lane holds q-col = lane&15, d-rows (lane>>4)*8..+8 (+32 for s=1)
    const __bf16* qrow = qp + ((size_t)(b * 2048 + qr0 + lq)) * 1024 + h * 64 + lg * 8;
    const bf16x8 qf0 = *(const bf16x8*)(qrow);
    const bf16x8 qf1 = *(const bf16x8*)(qrow + 32);

    const char* kBase = (const char*)(kp + (size_t)b * 2048 * 64);
    const char* vBase = (const char*)(vt + (size_t)b * 64 * 2048);

    float m = -1e30f, lsum = 0.f;

    // ---- pass A: row max + sumexp (online) ----
    for (int t = 0; t < 16; ++t) {
        __syncthreads();
        const char* ktb = kBase + (size_t)t * 128 * 128;
#pragma unroll
        for (int c = 0; c < 4; ++c) {
            int off = (w * 4 + c) * 1024 + l * 16;
            int r = off >> 7, cb = off & 127;
            gload_lds16(ktb + r * 128 + (cb ^ ((r & 7) << 4)), kLds + (w * 4 + c) * 1024);
        }
        asm volatile("s_waitcnt vmcnt(0)" ::: "memory");
        __syncthreads();

        f32x4 et[8];
        compute_et(kLds, qf0, qf1, lq, lg, et);

        float tmax = -1e30f;
#pragma unroll
        for (int kt = 0; kt < 8; ++kt)
#pragma unroll
            for (int r2 = 0; r2 < 4; ++r2) tmax = fmaxf(tmax, et[kt][r2]);
        tmax = fmaxf(tmax, __shfl_xor(tmax, 16));
        tmax = fmaxf(tmax, __shfl_xor(tmax, 32));
        const float mnew = fmaxf(m, tmax);
        float sl = 0.f;
#pragma unroll
        for (int kt = 0; kt < 8; ++kt)
#pragma unroll
            for (int r2 = 0; r2 < 4; ++r2) sl += __expf(et[kt][r2] - mnew);
        sl += __shfl_xor(sl, 16);
        sl += __shfl_xor(sl, 32);
        lsum = lsum * __expf(m - mnew) + sl;
        m = mnew;
    }
    const float inv_l = 1.0f / lsum;

    f32x4 cacc[4];
#pragma unroll
    for (int dt = 0; dt < 4; ++dt) cacc[dt] = (f32x4){0.f, 0.f, 0.f, 0.f};

    float* attn_row = attn_out + ((size_t)((b * 16 + h) * 2048 + qr0 + lq)) * 2048;

    // ---- pass B: recompute, write normalized attn, accumulate ctx ----
    for (int t = 0; t < 16; ++t) {
        __syncthreads();
        const char* ktb = kBase + (size_t)t * 128 * 128;
#pragma unroll
        for (int c = 0; c < 4; ++c) {
            int off = (w * 4 + c) * 1024 + l * 16;
            int r = off >> 7, cb = off & 127;
            gload_lds16(ktb + r * 128 + (cb ^ ((r & 7) << 4)), kLds + (w * 4 + c) * 1024);
        }
        const char* vtb = vBase + (size_t)t * 256;   // col offset t*128 elems within [64][2048]
#pragma unroll
        for (int c = 0; c < 4; ++c) {
            int off = (w * 4 + c) * 1024 + l * 16;
            int r = off >> 8, cb = off & 255;
            gload_lds16(vtb + (size_t)r * 4096 + (cb ^ ((r & 7) << 4)), vLds + (w * 4 + c) * 1024);
        }
        asm volatile("s_waitcnt vmcnt(0)" ::: "memory");
        __syncthreads();

        f32x4 et[8];
        compute_et(kLds, qf0, qf1, lq, lg, et);

        // p = exp(e - m) / l ; write attn (streaming) ; pack bf16 into per-wave P LDS
#pragma unroll
        for (int kt = 0; kt < 8; ++kt) {
            f32x4 p;
#pragma unroll
            for (int r2 = 0; r2 < 4; ++r2) p[r2] = __expf(et[kt][r2] - m) * inv_l;
            __builtin_nontemporal_store(p, (f32x4*)(attn_row + t * 128 + kt * 16 + lg * 4));
            bf16x4 pb;
#pragma unroll
            for (int r2 = 0; r2 < 4; ++r2) pb[r2] = (__bf16)p[r2];
            *(bf16x4*)(pLds + lq * 256 + ((kt * 32 + lg * 8) ^ ((lq & 7) << 4))) = pb;
        }

        // PV: ctx_T[d][q] += Vt[d][k] * P[q][k]
#pragma unroll
        for (int s = 0; s < 4; ++s) {
            bf16x8 pf = *(const bf16x8*)(pLds + lq * 256 + ((s * 64 + lg * 16) ^ ((lq & 7) << 4)));
#pragma unroll
            for (int dt = 0; dt < 4; ++dt) {
                int row = dt * 16 + lq;
                bf16x8 vf = *(const bf16x8*)(vLds + row * 256 + ((s * 64 + lg * 16) ^ ((row & 7) << 4)));
                cacc[dt] = mfma16(vf, pf, cacc[dt]);
            }
        }
    }

    // ctx write: lane col = q, rows = d within tile; 4 consecutive d -> 8B store
#pragma unroll
    for (int dt = 0; dt < 4; ++dt) {
        bf16x4 o;
#pragma unroll
        for (int r2 = 0; r2 < 4; ++r2) o[r2] = (__bf16)cacc[dt][r2];
        *(bf16x4*)(ctx + ((size_t)(b * 2048 + qr0 + lq)) * 1024 + h * 64 + dt * 16 + lg * 4) = o;
    }
}

extern "C" void kernel_launch(void* const* d_in, const int* in_sizes, int n_in,
                              void* d_out, int out_size, void* d_ws, size_t ws_size,
                              hipStream_t stream) {
    const float* query = (const float*)d_in[0];
    const float* key   = (const float*)d_in[1];
    const float* value = (const float*)d_in[2];
    const float* wq_w  = (const float*)d_in[3];
    const float* wq_b  = (const float*)d_in[4];
    const float* wk_w  = (const float*)d_in[5];
    const float* wk_b  = (const float*)d_in[6];
    const float* wv_w  = (const float*)d_in[7];
    const float* wv_b  = (const float*)d_in[8];
    const float* dw    = (const float*)d_in[9];
    const float* db    = (const float*)d_in[10];

    char* ws = (char*)d_ws;
    __bf16* qx  = (__bf16*)(ws);                              // 8MB  query bf16
    __bf16* kx  = (__bf16*)(ws + ((size_t)8 << 20));          // 8MB  key bf16
    __bf16* vx  = (__bf16*)(ws + ((size_t)16 << 20));         // 8MB  value bf16
    __bf16* qp  = (__bf16*)(ws + ((size_t)24 << 20));         // 8MB  q-proj (scaled)
    __bf16* ctx = (__bf16*)(ws + ((size_t)32 << 20));         // 8MB  context
    __bf16* wqT = (__bf16*)(ws + ((size_t)40 << 20));         // 2MB
    __bf16* dT  = (__bf16*)(ws + ((size_t)42 << 20));         // 2MB
    __bf16* wkT = (__bf16*)(ws + ((size_t)44 << 20));         // 128KB
    __bf16* wvT = (__bf16*)(ws + ((size_t)44 << 20) + (128 << 10));
    __bf16* kpb = (__bf16*)(ws + ((size_t)45 << 20));         // 512KB k-proj [4096][64]
    __bf16* vtb = (__bf16*)(ws + ((size_t)45 << 20) + (512 << 10)); // 512KB Vt [2][64][2048]

    float* out0 = (float*)d_out;
    float* attn = out0 + (size_t)4194304;

    cvt_f32_bf16<<<4096, 256, 0, stream>>>(query, qx);
    cvt_f32_bf16<<<4096, 256, 0, stream>>>(key, kx);
    cvt_f32_bf16<<<4096, 256, 0, stream>>>(value, vx);
    transpose_cvt<<<dim3(16, 16), 256, 0, stream>>>(wq_w, wqT, 1024, 1024);
    transpose_cvt<<<dim3(1, 16), 256, 0, stream>>>(wk_w, wkT, 1024, 64);
    transpose_cvt<<<dim3(1, 16), 256, 0, stream>>>(wv_w, wvT, 1024, 64);
    transpose_cvt<<<dim3(16, 16), 256, 0, stream>>>(dw, dT, 1024, 1024);

    gemm_kernel<128, 0><<<dim3(8, 32), 256, 0, stream>>>(qx, wqT, wq_b, qp);
    gemm_kernel<64, 1><<<dim3(1, 32), 256, 0, stream>>>(kx, wkT, wk_b, kpb);
    gemm_kernel<64, 2><<<dim3(1, 32), 256, 0, stream>>>(vx, wvT, wv_b, vtb);

    attn_fused<<<dim3(32, 16, 2), 256, 0, stream>>>(qp, kpb, vtb, attn, ctx);

    gemm_kernel<128, 3><<<dim3(8, 32), 256, 0, stream>>>(ctx, dT, db, out0);
}